// Round 9
// baseline (756.444 us; speedup 1.0000x reference)
//
#include <hip/hip_runtime.h>
#include <hip/hip_bf16.h>
#include <hip/hip_fp16.h>
#include <stdint.h>

// Problem constants (QLoRALinear_34454227649197)
#define M_DIM 16384   // TOK
#define N_DIM 4096    // OUT
#define K_DIM 4096    // IN
#define NGROUP 64     // K_DIM / 64
#define NT    64      // K-tiles (K_DIM / 64)

// Harness dtype note (round-3 forensics): float16 arrays are presented as
// FLOAT32 on device. x = const float*, out = float*.

typedef _Float16 f16x8 __attribute__((ext_vector_type(8)));
typedef _Float16 f16x2 __attribute__((ext_vector_type(2)));
typedef float f32x4 __attribute__((ext_vector_type(4)));

typedef __attribute__((address_space(3))) uint32_t lds_u32_t;
typedef const __attribute__((address_space(1))) uint32_t glob_u32_t;

__device__ __forceinline__ void gload16(const void* g, void* l) {
    // global_load_lds_dwordx4: LDS dest = wave-uniform base + lane*16;
    // global source per-lane (pre-swizzled). Zero conflicts, rounds 5-8.
    __builtin_amdgcn_global_load_lds((glob_u32_t*)g, (lds_u32_t*)l, 16, 0, 0);
}

// ---------------------------------------------------------------------------
// Kernel 0: Xh[i] = (fp16) x[i]   (exact: x values are fp16-quantized)
// ---------------------------------------------------------------------------
__global__ __launch_bounds__(256) void convert_x_kernel(
    const float* __restrict__ x, _Float16* __restrict__ Xh)
{
    const size_t i = ((size_t)blockIdx.x * 256 + threadIdx.x) * 8;
    const float4 a = *reinterpret_cast<const float4*>(&x[i]);
    const float4 b = *reinterpret_cast<const float4*>(&x[i + 4]);
    f16x8 o;
    o[0] = (_Float16)a.x; o[1] = (_Float16)a.y;
    o[2] = (_Float16)a.z; o[3] = (_Float16)a.w;
    o[4] = (_Float16)b.x; o[5] = (_Float16)b.y;
    o[6] = (_Float16)b.z; o[7] = (_Float16)b.w;
    *reinterpret_cast<f16x8*>(&Xh[i]) = o;
}

// ---------------------------------------------------------------------------
// Kernel 1: W[local n][k] = (q[n0+n][k]-8)*scales[n0+n][k/64]
//                           + sum_r lB[n0+n][r]*lA[r][k]     (fp16 out)
// ---------------------------------------------------------------------------
__global__ __launch_bounds__(256) void dequant_lora_kernel(
    const int* __restrict__ q, const float* __restrict__ sc,
    const float* __restrict__ lA, const float* __restrict__ lB,
    _Float16* __restrict__ W, int n0)
{
    const int t   = threadIdx.x;
    const int o0l = blockIdx.x * 4;        // local chunk row base
    const int o0g = n0 + o0l;              // global OUT row base

    __shared__ float sScale[4][64];
    __shared__ float sB[4][16];
    sScale[t >> 6][t & 63] = sc[(size_t)(o0g + (t >> 6)) * NGROUP + (t & 63)];
    if (t < 64) sB[t >> 4][t & 15] = lB[(size_t)(o0g + (t >> 4)) * 16 + (t & 15)];
    __syncthreads();

    for (int j = 0; j < 8; ++j) {
        const int i = j * 512 + t * 2;      // even; covers [0,4096)
        float l0[4] = {0.f, 0.f, 0.f, 0.f};
        float l1[4] = {0.f, 0.f, 0.f, 0.f};
        #pragma unroll
        for (int r = 0; r < 16; ++r) {
            const float2 a = *reinterpret_cast<const float2*>(&lA[(size_t)r * K_DIM + i]);
            #pragma unroll
            for (int row = 0; row < 4; ++row) {
                l0[row] = fmaf(sB[row][r], a.x, l0[row]);
                l1[row] = fmaf(sB[row][r], a.y, l1[row]);
            }
        }
        const int g = i >> 6;               // i even => i, i+1 same group
        #pragma unroll
        for (int row = 0; row < 4; ++row) {
            const int2 qv = *reinterpret_cast<const int2*>(&q[(size_t)(o0g + row) * K_DIM + i]);
            const float s = sScale[row][g];
            f16x2 h2;
            h2[0] = (_Float16)fmaf((float)(qv.x - 8), s, l0[row]);
            h2[1] = (_Float16)fmaf((float)(qv.y - 8), s, l1[row]);
            *reinterpret_cast<f16x2*>(&W[(size_t)(o0l + row) * K_DIM + i]) = h2;
        }
    }
}

// ---------------------------------------------------------------------------
// Kernel 2: out = Xh @ W^T — 256x256, BK=64, 8 waves (2M x 4N, 128x64/wave).
// WAVE-PRIVATE STAGING + COUNTED VMCNT (T4): each wave redundantly stages
// exactly the LDS region it reads (A-half[wr]: 16 gloads, B-quarter[wc]: 8),
// peers write byte-identical data (benign). Staged->read RAW is then
// per-wave: gate = s_waitcnt vmcnt(24) (own next-tile loads outstanding),
// NEVER a drain. Barrier = raw s_barrier (WAR only, no waitcnt): peers'
// staged writes proven landed by their own previous gate + this barrier.
// Round-7 compiler-scheduled compute body (round-8 fences regressed).
// ---------------------------------------------------------------------------
#define ABUF 32768                    // A: 256 rows x 128 B
#define BUF_BYTES 65536               // A (32K) + B (32K)

__global__ __launch_bounds__(512, 2) void gemm_bt_kernel(
    const _Float16* __restrict__ A,   // Xh chunk, [rows][K]
    const _Float16* __restrict__ B,   // W chunk,  [cols][K]
    float* __restrict__ C,
    int m0, int n0, int nbm, int nbn)
{
    alignas(16) __shared__ _Float16 lds[2 * 32768];   // 128 KiB

    const int t  = threadIdx.x;
    const int l  = t & 63;
    const int w  = t >> 6;          // 0..7
    const int wr = w >> 2;          // 0..1  (M: 128 rows)
    const int wc = w & 3;           // 0..3  (N: 64 cols)

    // m204 bijective XCD swizzle, then tail-safe GROUP_M=8.
    const int nwg  = nbm * nbn;
    const int orig = blockIdx.x;
    const int xcd  = orig & 7;
    const int qq = nwg >> 3, rr = nwg & 7;
    const int wg = (xcd < rr ? xcd * (qq + 1) : rr * (qq + 1) + (xcd - rr) * qq)
                 + (orig >> 3);
    const int gs    = 8 * nbn;
    const int group = wg / gs;
    const int start = group * 8;
    const int gsz   = (nbm - start < 8) ? (nbm - start) : 8;
    const int idg   = wg - group * gs;
    const int bm    = start + idg % gsz;
    const int bn    = idg / gsz;

    const int Mb = bm * 256;
    const int Nb = bn * 256;

    // Wave-private staging geometry: lane l covers row-slice lr = l>>3 of
    // each 8-row issue, physical k-slot l&7; swizzled source k-off =
    // ((l&7)^lr)*8 elems (row&7 == lr for all issue rows). LDS dest is
    // wave-uniform base + l*16 (linear) -- gload_lds contract satisfied.
    const int lr = l >> 3;                     // 0..7
    const int lk = ((l & 7) ^ lr) * 8;         // swizzled k-offset (elems)
    const _Float16* aSrcW = A + (size_t)(Mb + wr * 128 + lr) * K_DIM + lk;
    const _Float16* bSrcW = B + (size_t)(Nb + wc * 64  + lr) * K_DIM + lk;
    char* const ldsBase = (char*)lds;
    const int aDoff = wr * 16384 + l * 16;           // within A region
    const int bDoff = ABUF + wc * 8192 + l * 16;     // within B region

    const int r16 = l & 15;
    const int hi  = l >> 4;           // 0..3
    const int swzB = (r16 & 7) * 16;  // row-dependent XOR part (bytes)

    f32x4 acc[8][4] = {};

    // STAGE(tile kt1): 24 wave-private gloads (A-half 16, B-quarter 8).
    auto STAGE = [&](int kt1) {
        char* bb = ldsBase + ((kt1 & 1) * BUF_BYTES);
        char* ad = bb + aDoff;
        char* bd = bb + bDoff;
        const int kp = kt1 * 64;
        #pragma unroll
        for (int j = 0; j < 16; ++j)
            gload16(aSrcW + (size_t)(j * 8) * K_DIM + kp, ad + j * 1024);
        #pragma unroll
        for (int j = 0; j < 8; ++j)
            gload16(bSrcW + (size_t)(j * 8) * K_DIM + kp, bd + j * 1024);
    };

    STAGE(0);

    for (int kt = 0; kt < NT; ++kt) {
        // WAR fence only: no waitcnt drain. Separates last tile's LDS reads
        // from restaging of that buffer below.
        __builtin_amdgcn_s_barrier();
        __builtin_amdgcn_sched_barrier(0);

        if (kt + 1 < NT) {
            STAGE(kt + 1);
            __builtin_amdgcn_sched_barrier(0);
            // Counted gate: own outstanding = 24 (kt+1) + 24 (kt, issued one
            // full tile ago). Wait to <=24 => tile kt landed. Never 0.
            asm volatile("s_waitcnt vmcnt(24)" ::: "memory");
        } else {
            asm volatile("s_waitcnt vmcnt(0)" ::: "memory");
        }
        __builtin_amdgcn_sched_barrier(0);

        const char* Ac = ldsBase + (kt & 1) * BUF_BYTES;
        const char* Bc = Ac + ABUF;

        // Compute tile kt (compiler-scheduled; round-7 body).
        #pragma unroll
        for (int ks = 0; ks < 2; ++ks) {
            f16x8 bF[4];
            const int swz = ((ks * 4 + hi) * 16) ^ swzB;
            #pragma unroll
            for (int i = 0; i < 4; ++i)
                bF[i] = *(const f16x8*)(Bc + (wc * 64 + i * 16 + r16) * 128 + swz);
            #pragma unroll
            for (int mq = 0; mq < 2; ++mq) {
                f16x8 aF[4];
                #pragma unroll
                for (int i = 0; i < 4; ++i)
                    aF[i] = *(const f16x8*)(Ac + (wr * 128 + mq * 64 + i * 16 + r16) * 128 + swz);
                __builtin_amdgcn_s_setprio(1);
                #pragma unroll
                for (int mi = 0; mi < 4; ++mi)
                    #pragma unroll
                    for (int ni = 0; ni < 4; ++ni)
                        acc[mq * 4 + mi][ni] = __builtin_amdgcn_mfma_f32_16x16x32_f16(
                            aF[mi], bF[ni], acc[mq * 4 + mi][ni], 0, 0, 0);
                __builtin_amdgcn_s_setprio(0);
            }
        }
    }

    // Epilogue: C/D layout col = lane&15, row = (lane>>4)*4 + reg. f32 stores.
    #pragma unroll
    for (int mi = 0; mi < 8; ++mi) {
        const int row0 = m0 + Mb + wr * 128 + mi * 16 + hi * 4;
        #pragma unroll
        for (int ni = 0; ni < 4; ++ni) {
            const int col = n0 + Nb + wc * 64 + ni * 16 + r16;
            const f32x4 v = acc[mi][ni];
            #pragma unroll
            for (int u = 0; u < 4; ++u)
                C[(size_t)(row0 + u) * N_DIM + col] = v[u];
        }
    }
}

extern "C" void kernel_launch(void* const* d_in, const int* in_sizes, int n_in,
                              void* d_out, int out_size, void* d_ws, size_t ws_size,
                              hipStream_t stream) {
    const float* x  = (const float*)d_in[0];   // fp16 values promoted to f32
    const int*   q  = (const int*)d_in[1];
    const float* sc = (const float*)d_in[2];
    const float* lA = (const float*)d_in[3];
    const float* lB = (const float*)d_in[4];
    float* out = (float*)d_out;                 // f32 output buffer

    // Workspace layout: [W: colC x K fp16][Xh: rowC x K fp16], chunk-looped.
    const size_t wfull = (size_t)N_DIM * K_DIM * 2;   // 32 MiB
    int colC, rowC;
    if (ws_size >= wfull + (size_t)256 * K_DIM * 2) {
        colC = N_DIM;
        size_t rows = (ws_size - wfull) / ((size_t)K_DIM * 2);
        rowC = (int)((rows / 256) * 256);
        if (rowC > M_DIM) rowC = M_DIM;
    } else {
        size_t half = ws_size / 2;
        colC = (int)((half / ((size_t)K_DIM * 2) / 256) * 256);
        if (colC < 256) colC = 256;
        if (colC > N_DIM) colC = N_DIM;
        size_t rows = (ws_size - (size_t)colC * K_DIM * 2) / ((size_t)K_DIM * 2);
        rowC = (int)((rows / 256) * 256);
        if (rowC < 256) rowC = 256;
        if (rowC > M_DIM) rowC = M_DIM;
    }
    _Float16* W  = (_Float16*)d_ws;
    _Float16* Xh = (_Float16*)d_ws + (size_t)colC * K_DIM;

    for (int n0 = 0; n0 < N_DIM; n0 += colC) {
        int cols = N_DIM - n0; if (cols > colC) cols = colC;
        dequant_lora_kernel<<<cols / 4, 256, 0, stream>>>(q, sc, lA, lB, W, n0);
        for (int m0 = 0; m0 < M_DIM; m0 += rowC) {
            int rows = M_DIM - m0; if (rows > rowC) rows = rowC;
            convert_x_kernel<<<(int)(((size_t)rows * K_DIM) / (256 * 8)), 256, 0, stream>>>(
                x + (size_t)m0 * K_DIM, Xh);
            gemm_bt_kernel<<<(rows / 256) * (cols / 256), 512, 0, stream>>>(
                Xh, W, out, m0, n0, rows / 256, cols / 256);
        }
    }
}

// Round 10
// 597.006 us; speedup vs baseline: 1.2671x; 1.2671x over previous
//
#include <hip/hip_runtime.h>
#include <hip/hip_bf16.h>
#include <hip/hip_fp16.h>
#include <stdint.h>

// Problem constants (QLoRALinear_34454227649197)
#define M_DIM 16384   // TOK
#define N_DIM 4096    // OUT
#define K_DIM 4096    // IN
#define NGROUP 64     // K_DIM / 64
#define NT    64      // K-tiles (K_DIM / 64)

// Harness dtype note (round-3 forensics): float16 arrays are presented as
// FLOAT32 on device. x = const float*, out = float*.

typedef _Float16 f16x8 __attribute__((ext_vector_type(8)));
typedef _Float16 f16x2 __attribute__((ext_vector_type(2)));
typedef float f32x4 __attribute__((ext_vector_type(4)));

typedef __attribute__((address_space(3))) uint32_t lds_u32_t;
typedef const __attribute__((address_space(1))) uint32_t glob_u32_t;

__device__ __forceinline__ void gload16(const void* g, void* l) {
    // global_load_lds_dwordx4: LDS dest = wave-uniform base + lane*16;
    // global source per-lane (pre-swizzled). Zero conflicts rounds 5-9.
    __builtin_amdgcn_global_load_lds((glob_u32_t*)g, (lds_u32_t*)l, 16, 0, 0);
}

// ---------------------------------------------------------------------------
// Kernel 0: Xh[i] = (fp16) x[i]   (exact: x values are fp16-quantized)
// ---------------------------------------------------------------------------
__global__ __launch_bounds__(256) void convert_x_kernel(
    const float* __restrict__ x, _Float16* __restrict__ Xh)
{
    const size_t i = ((size_t)blockIdx.x * 256 + threadIdx.x) * 8;
    const float4 a = *reinterpret_cast<const float4*>(&x[i]);
    const float4 b = *reinterpret_cast<const float4*>(&x[i + 4]);
    f16x8 o;
    o[0] = (_Float16)a.x; o[1] = (_Float16)a.y;
    o[2] = (_Float16)a.z; o[3] = (_Float16)a.w;
    o[4] = (_Float16)b.x; o[5] = (_Float16)b.y;
    o[6] = (_Float16)b.z; o[7] = (_Float16)b.w;
    *reinterpret_cast<f16x8*>(&Xh[i]) = o;
}

// ---------------------------------------------------------------------------
// Kernel 1: W[local n][k] = (q[n0+n][k]-8)*scales[n0+n][k/64]
//                           + sum_r lB[n0+n][r]*lA[r][k]     (fp16 out)
// ---------------------------------------------------------------------------
__global__ __launch_bounds__(256) void dequant_lora_kernel(
    const int* __restrict__ q, const float* __restrict__ sc,
    const float* __restrict__ lA, const float* __restrict__ lB,
    _Float16* __restrict__ W, int n0)
{
    const int t   = threadIdx.x;
    const int o0l = blockIdx.x * 4;        // local chunk row base
    const int o0g = n0 + o0l;              // global OUT row base

    __shared__ float sScale[4][64];
    __shared__ float sB[4][16];
    sScale[t >> 6][t & 63] = sc[(size_t)(o0g + (t >> 6)) * NGROUP + (t & 63)];
    if (t < 64) sB[t >> 4][t & 15] = lB[(size_t)(o0g + (t >> 4)) * 16 + (t & 15)];
    __syncthreads();

    for (int j = 0; j < 8; ++j) {
        const int i = j * 512 + t * 2;      // even; covers [0,4096)
        float l0[4] = {0.f, 0.f, 0.f, 0.f};
        float l1[4] = {0.f, 0.f, 0.f, 0.f};
        #pragma unroll
        for (int r = 0; r < 16; ++r) {
            const float2 a = *reinterpret_cast<const float2*>(&lA[(size_t)r * K_DIM + i]);
            #pragma unroll
            for (int row = 0; row < 4; ++row) {
                l0[row] = fmaf(sB[row][r], a.x, l0[row]);
                l1[row] = fmaf(sB[row][r], a.y, l1[row]);
            }
        }
        const int g = i >> 6;               // i even => i, i+1 same group
        #pragma unroll
        for (int row = 0; row < 4; ++row) {
            const int2 qv = *reinterpret_cast<const int2*>(&q[(size_t)(o0g + row) * K_DIM + i]);
            const float s = sScale[row][g];
            f16x2 h2;
            h2[0] = (_Float16)fmaf((float)(qv.x - 8), s, l0[row]);
            h2[1] = (_Float16)fmaf((float)(qv.y - 8), s, l1[row]);
            *reinterpret_cast<f16x2*>(&W[(size_t)(o0l + row) * K_DIM + i]) = h2;
        }
    }
}

// ---------------------------------------------------------------------------
// Kernel 2: out = Xh @ W^T — 256x256, BK=64, 8 waves (2M x 4N, 128x64/wave).
// m201-style 8-PHASE schedule (4 phases/K-tile, 2 barriers/phase, raw
// s_barrier, COUNTED vmcnt(4) at phase 4 only). Liveness ledger:
//   - All A-fragment ds_reads front-loaded in P1/P2 -> A region of buf[kt&1]
//     dead after P2-end barrier -> P3/P4 restage kt+2's A-halves into it.
//   - B halves of kt+1 staged in P1/P2 (into buf[kt+1&1], disjoint).
//   - Gate at P4: outstanding = {kt+1 Bh0,Bh1, kt+2 Ah0,Ah1} = 8 loads;
//     vmcnt(4) retires kt+1's B (its A retired at kt-1's gate) -> tile kt+1
//     fully resident before its P1. Never a full drain in the main loop.
// Shared staging (8 gload16/thread/tile, round-7 volume). Zero-conflict
// XOR swizzle throughout (rounds 5-9).
// ---------------------------------------------------------------------------
#define ABUF 32768                    // A region: 256 rows x 128 B
#define BUF_BYTES 65536               // A (32K) + B (32K)
#define NT4 (NT * 4)

#define RD_A(dst, mq, ks) do {                                              \
    const int swz_ = ((((ks) * 4 + hi) * 16) ^ swzB);                       \
    _Pragma("unroll")                                                       \
    for (int i_ = 0; i_ < 4; ++i_)                                          \
        dst[i_] = *(const f16x8*)(Ac +                                      \
            (wr * 128 + (mq) * 64 + i_ * 16 + r16) * 128 + swz_);           \
} while (0)

#define RD_B(dst, ks) do {                                                  \
    const int swz_ = ((((ks) * 4 + hi) * 16) ^ swzB);                       \
    _Pragma("unroll")                                                       \
    for (int i_ = 0; i_ < 4; ++i_)                                          \
        dst[i_] = *(const f16x8*)(Bc +                                      \
            (wc * 64 + i_ * 16 + r16) * 128 + swz_);                        \
} while (0)

#define MFMA16(aF, bF, mq) do {                                             \
    __builtin_amdgcn_s_setprio(1);                                          \
    _Pragma("unroll")                                                       \
    for (int mi_ = 0; mi_ < 4; ++mi_)                                       \
        _Pragma("unroll")                                                   \
        for (int ni_ = 0; ni_ < 4; ++ni_)                                   \
            acc[(mq) * 4 + mi_][ni_] = __builtin_amdgcn_mfma_f32_16x16x32_f16( \
                aF[mi_], bF[ni_], acc[(mq) * 4 + mi_][ni_], 0, 0, 0);       \
    __builtin_amdgcn_s_setprio(0);                                          \
} while (0)

__global__ __launch_bounds__(512, 2) void gemm_bt_kernel(
    const _Float16* __restrict__ A,   // Xh chunk, [rows][K]
    const _Float16* __restrict__ B,   // W chunk,  [cols][K]
    float* __restrict__ C,
    int m0, int n0, int nbm, int nbn)
{
    alignas(16) __shared__ _Float16 lds[2 * 32768];   // 128 KiB

    const int t  = threadIdx.x;
    const int l  = t & 63;
    const int w  = t >> 6;          // 0..7
    const int wr = w >> 2;          // 0..1  (M: 128 rows)
    const int wc = w & 3;           // 0..3  (N: 64 cols)

    // m204 bijective XCD swizzle, then tail-safe GROUP_M=8.
    const int nwg  = nbm * nbn;
    const int orig = blockIdx.x;
    const int xcd  = orig & 7;
    const int qq = nwg >> 3, rr = nwg & 7;
    const int wg = (xcd < rr ? xcd * (qq + 1) : rr * (qq + 1) + (xcd - rr) * qq)
                 + (orig >> 3);
    const int gs    = 8 * nbn;
    const int group = wg / gs;
    const int start = group * 8;
    const int gsz   = (nbm - start < 8) ? (nbm - start) : 8;
    const int idg   = wg - group * gs;
    const int bm    = start + idg % gsz;
    const int bn    = idg / gsz;

    const int Mb = bm * 256;
    const int Nb = bn * 256;

    // Shared staging: 512 thr x 16B = 8 KB = 64 rows x 128 B per issue.
    const int rloc = t >> 3;                   // 0..63
    const int kswz = ((t & 7) ^ (rloc & 7)) * 8;
    const _Float16* aSrc = A + (size_t)(Mb + rloc) * K_DIM + kswz;
    const _Float16* bSrc = B + (size_t)(Nb + rloc) * K_DIM + kswz;
    char* const ldsBase = (char*)lds;
    const int dOff = t * 16;

    const int r16 = l & 15;
    const int hi  = l >> 4;           // 0..3
    const int swzB = (r16 & 7) * 16;  // row-dependent XOR part (bytes)

    // STAGEH(j): stage global half-tile j (= kt*4 + h; h: 0=Ah0,1=Ah1,
    // 2=Bh0,3=Bh1) into buf[(j>>2)&1]. 2 gload16/thread (128 rows).
    auto STAGEH = [&](int j) {
        if (j >= NT4) return;
        const int ktj = j >> 2, h = j & 3;
        const _Float16* src = ((h >> 1) ? bSrc : aSrc)
                            + (size_t)((h & 1) * 128) * K_DIM + ktj * 64;
        char* d = ldsBase + (ktj & 1) * BUF_BYTES
                + ((h >> 1) ? ABUF : 0) + (h & 1) * 16384 + dOff;
        gload16(src, d);
        gload16(src + (size_t)64 * K_DIM, d + 8192);
    };

    f32x4 acc[8][4] = {};
    f16x8 aF0[4], aF1[4], aF2[4], aF3[4], bF0[4], bF1[4];

    // Prologue: kt0 h0-h3 + kt1 h0,h1 (A halves); counted wait; publish.
    STAGEH(0); STAGEH(1); STAGEH(2); STAGEH(3); STAGEH(4); STAGEH(5);
    asm volatile("s_waitcnt vmcnt(4)" ::: "memory");   // kt0 landed
    __builtin_amdgcn_s_barrier();

    for (int kt = 0; kt < NT; ++kt) {
        const char* Ac = ldsBase + (kt & 1) * BUF_BYTES;
        const char* Bc = Ac + ABUF;
        const int j1 = 4 * (kt + 1), j2 = 4 * (kt + 2);

        // P1: read bF0 + aF0 (8 ds_read); stage kt+1 Bh0.
        RD_B(bF0, 0);
        RD_A(aF0, 0, 0);
        STAGEH(j1 + 2);
        __builtin_amdgcn_s_barrier();
        MFMA16(aF0, bF0, 0);
        __builtin_amdgcn_s_barrier();

        // P2: read aF1,aF2,aF3 (12 ds_read; all A reads done after this);
        //     stage kt+1 Bh1.
        RD_A(aF1, 1, 0);
        RD_A(aF2, 0, 1);
        RD_A(aF3, 1, 1);
        STAGEH(j1 + 3);
        __builtin_amdgcn_s_barrier();
        MFMA16(aF1, bF0, 1);
        __builtin_amdgcn_s_barrier();

        // P3: A region of buf[kt&1] now dead -> restage kt+2 Ah0 into it.
        //     Read bF1 (B region, disjoint).
        __builtin_amdgcn_sched_barrier(0);   // pin P2 reads above this stage
        STAGEH(j2 + 0);
        RD_B(bF1, 1);
        __builtin_amdgcn_s_barrier();
        MFMA16(aF2, bF1, 0);
        __builtin_amdgcn_s_barrier();

        // P4: stage kt+2 Ah1; counted gate; pure-register MFMA.
        STAGEH(j2 + 1);
        if (kt + 2 < NT) {
            asm volatile("s_waitcnt vmcnt(4)" ::: "memory");  // kt+1 resident
        } else if (kt + 1 < NT) {
            asm volatile("s_waitcnt vmcnt(0)" ::: "memory");  // final fill
        }
        __builtin_amdgcn_s_barrier();
        MFMA16(aF3, bF1, 1);
        __builtin_amdgcn_s_barrier();
    }

    // Epilogue: C/D layout col = lane&15, row = (lane>>4)*4 + reg. f32 stores.
    #pragma unroll
    for (int mi = 0; mi < 8; ++mi) {
        const int row0 = m0 + Mb + wr * 128 + mi * 16 + hi * 4;
        #pragma unroll
        for (int ni = 0; ni < 4; ++ni) {
            const int col = n0 + Nb + wc * 64 + ni * 16 + r16;
            const f32x4 v = acc[mi][ni];
            #pragma unroll
            for (int u = 0; u < 4; ++u)
                C[(size_t)(row0 + u) * N_DIM + col] = v[u];
        }
    }
}

extern "C" void kernel_launch(void* const* d_in, const int* in_sizes, int n_in,
                              void* d_out, int out_size, void* d_ws, size_t ws_size,
                              hipStream_t stream) {
    const float* x  = (const float*)d_in[0];   // fp16 values promoted to f32
    const int*   q  = (const int*)d_in[1];
    const float* sc = (const float*)d_in[2];
    const float* lA = (const float*)d_in[3];
    const float* lB = (const float*)d_in[4];
    float* out = (float*)d_out;                 // f32 output buffer

    // Workspace layout: [W: colC x K fp16][Xh: rowC x K fp16], chunk-looped.
    const size_t wfull = (size_t)N_DIM * K_DIM * 2;   // 32 MiB
    int colC, rowC;
    if (ws_size >= wfull + (size_t)256 * K_DIM * 2) {
        colC = N_DIM;
        size_t rows = (ws_size - wfull) / ((size_t)K_DIM * 2);
        rowC = (int)((rows / 256) * 256);
        if (rowC > M_DIM) rowC = M_DIM;
    } else {
        size_t half = ws_size / 2;
        colC = (int)((half / ((size_t)K_DIM * 2) / 256) * 256);
        if (colC < 256) colC = 256;
        if (colC > N_DIM) colC = N_DIM;
        size_t rows = (ws_size - (size_t)colC * K_DIM * 2) / ((size_t)K_DIM * 2);
        rowC = (int)((rows / 256) * 256);
        if (rowC < 256) rowC = 256;
        if (rowC > M_DIM) rowC = M_DIM;
    }
    _Float16* W  = (_Float16*)d_ws;
    _Float16* Xh = (_Float16*)d_ws + (size_t)colC * K_DIM;

    for (int n0 = 0; n0 < N_DIM; n0 += colC) {
        int cols = N_DIM - n0; if (cols > colC) cols = colC;
        dequant_lora_kernel<<<cols / 4, 256, 0, stream>>>(q, sc, lA, lB, W, n0);
        for (int m0 = 0; m0 < M_DIM; m0 += rowC) {
            int rows = M_DIM - m0; if (rows > rowC) rows = rowC;
            convert_x_kernel<<<(int)(((size_t)rows * K_DIM) / (256 * 8)), 256, 0, stream>>>(
                x + (size_t)m0 * K_DIM, Xh);
            gemm_bt_kernel<<<(rows / 256) * (cols / 256), 512, 0, stream>>>(
                Xh, W, out, m0, n0, rows / 256, cols / 256);
        }
    }
}